// Round 7
// baseline (490.231 us; speedup 1.0000x reference)
//
#include <hip/hip_runtime.h>
#include <hip/hip_bf16.h>

#define M_TOK 8192
#define N_OUT 4096
#define K_IN  4096

typedef __attribute__((ext_vector_type(8))) short bf16x8;
typedef __attribute__((ext_vector_type(4))) float f32x4;
typedef unsigned short u16;

// fp32 -> bf16 RNE (finite inputs)
__device__ static inline u16 f2bf(float f) {
    union { float f; unsigned int u; } v; v.f = f;
    unsigned int u = v.u;
    u += 0x7FFFu + ((u >> 16) & 1u);
    return (u16)(u >> 16);
}

__device__ static inline void load_lds16(const void* g, void* l) {
    __builtin_amdgcn_global_load_lds(
        (const __attribute__((address_space(1))) unsigned int*)g,
        (__attribute__((address_space(3))) unsigned int*)l,
        16, 0, 0);
}

// ---------------- fused prep pass (memory-bound, ~HBM roofline) -----------
__global__ void prep_kernel(const float* __restrict__ x,
                            const float* __restrict__ mean,
                            const float* __restrict__ sigma,
                            const float* __restrict__ noise,
                            const int* __restrict__ smult,
                            u16* __restrict__ xb, u16* __restrict__ wb) {
    if (blockIdx.x < 2048) {
        const int n4 = (M_TOK * K_IN) / 4;
        int i = blockIdx.x * blockDim.x + threadIdx.x;
        const int stride = 2048 * 256;
        for (int e = i; e < n4; e += stride) {
            float4 v = reinterpret_cast<const float4*>(x)[e];
            ushort4 o;
            o.x = f2bf(v.x); o.y = f2bf(v.y); o.z = f2bf(v.z); o.w = f2bf(v.w);
            reinterpret_cast<ushort4*>(xb)[e] = o;
        }
    } else {
        const float sm = (float)(*smult);
        const int n4 = (N_OUT * K_IN) / 4;
        int i = (blockIdx.x - 2048) * blockDim.x + threadIdx.x;
        const int stride = 1024 * 256;
        for (int e = i; e < n4; e += stride) {
            float4 m = reinterpret_cast<const float4*>(mean)[e];
            float4 s = reinterpret_cast<const float4*>(sigma)[e];
            float4 z = reinterpret_cast<const float4*>(noise)[e];
            ushort4 o;
            o.x = f2bf(m.x * (1.0f + z.x * fabsf(s.x) * sm));
            o.y = f2bf(m.y * (1.0f + z.y * fabsf(s.y) * sm));
            o.z = f2bf(m.z * (1.0f + z.z * fabsf(s.z) * sm));
            o.w = f2bf(m.w * (1.0f + z.w * fabsf(s.w) * sm));
            reinterpret_cast<ushort4*>(wb)[e] = o;
        }
    }
}

// ------ 256x256 GEMM: A via LDS (dbuf), B direct global->reg, 1 bar/K-tile -
// C[t][o] = sum_k A[t][k]*B[o][k] + bias[o]; A=[M][K] bf16, B=[N][K] bf16.
// LDS (A only): [buf(2)][half(2)][8192 elem] = 64 KiB. 16B-slot swizzle
// slot^=(row&7) on global src of global_load_lds + on ds_read (0 conflicts).
// Per K-tile: { load B(t,k1) + stage A(t+1) + prefetch B(t+1,k0) ;
//   16 ds_read A-frags ; 64 MFMA (compiler-counted vmcnt/lgkm deps) ;
//   vmcnt(0) [all issued >=1 tile or >=32-MFMA earlier -> ~free] ; barrier }.
// No intra-tile barriers: 8 waves skew, LDS (~1600cy) hides under MFMA (~2500cy).

#define BARM()  { __builtin_amdgcn_s_barrier(); asm volatile("" ::: "memory"); }
#define VMC0()  asm volatile("s_waitcnt vmcnt(0)" ::: "memory")

#define DS_A4(AR, MG, AB) \
  _Pragma("unroll") for (int m_ = 0; m_ < 4; ++m_) { \
    AR[m_][0] = *reinterpret_cast<const bf16x8*>((AB) + ((MG)+m_)*1024 + aoff0); \
    AR[m_][1] = *reinterpret_cast<const bf16x8*>((AB) + ((MG)+m_)*1024 + aoff1); }

// B fragment loads: frag n covers cols [.. + n*16), k-chunk kk*32 + la_hi*8
#define LD_BF(DST, T, KK) \
  _Pragma("unroll") for (int n_ = 0; n_ < 4; ++n_) \
    DST[n_] = *reinterpret_cast<const bf16x8*>( \
        Bq + (size_t)n_ * (16 * K_IN) + (T) * 64 + (KK) * 32);

#define MF16(MG, KK, BF) \
  __builtin_amdgcn_s_setprio(1); \
  _Pragma("unroll") for (int m_ = 0; m_ < 4; ++m_) \
  _Pragma("unroll") for (int n_ = 0; n_ < 4; ++n_) \
    acc[(MG)+m_][n_] = __builtin_amdgcn_mfma_f32_16x16x32_bf16( \
        aR[m_][KK], BF[n_], acc[(MG)+m_][n_], 0, 0, 0); \
  __builtin_amdgcn_s_setprio(0);

#define STAGE_A(T, H, BUF) { \
  const u16* g_ = Abase + (size_t)((H)*128 + srow) * K_IN + (T)*64 + sxcol; \
  load_lds16(g_, smem + (BUF)*16384 + (H)*8192 + tid*8); \
  load_lds16(g_ + (size_t)64*K_IN, smem + (BUF)*16384 + (H)*8192 + 4096 + tid*8); }

// One K-tile: read buf RB, stage A(t+1)->WB; BK0 = B(t,k0) (prefetched),
// BK1 <- B(t,k1), BN0 <- B(t+1,k0) prefetch.
#define TILE(T, RB, WB, BK0, BK1, BN0) { \
  const int tnx_ = ((T) < 63) ? (T) + 1 : 63; \
  LD_BF(BK1, T, 1); \
  STAGE_A(tnx_, 0, WB); \
  STAGE_A(tnx_, 1, WB); \
  LD_BF(BN0, tnx_, 0); \
  const u16* Ab_ = smem + (RB)*16384 + wm*8192; \
  DS_A4(aR, 0, Ab_); \
  MF16(0, 0, BK0); \
  MF16(0, 1, BK1); \
  DS_A4(aR, 4, Ab_); \
  MF16(4, 0, BK0); \
  MF16(4, 1, BK1); \
  VMC0(); \
  BARM(); }

__global__ __launch_bounds__(512, 2)
void gemm_bias_kernel(const u16* __restrict__ A, const u16* __restrict__ B,
                      const float* __restrict__ bias, float* __restrict__ C) {
    __shared__ u16 smem[32768];   // 64 KiB, A only

    const int tid   = threadIdx.x;
    const int lane  = tid & 63;
    const int wid   = tid >> 6;
    const int wm    = wid >> 2;      // 0..1  (M half, 128 rows)
    const int wn    = wid & 3;       // 0..3  (N slice, 64 cols)
    const int la_lo = lane & 15;
    const int la_hi = lane >> 4;

    // T1 v2: per-XCD 2D rectangle (FETCH 197 MB measured, keep)
    const int bid = blockIdx.x;
    const int xcd = bid & 7;
    const int c   = bid >> 3;
    const int r   = c >> 5;
    const int s   = c & 31;
    const int bm  = xcd * 4 + (s & 3);
    const int bn  = r * 8 + (s >> 2);
    const int brow = bm * 256;
    const int bcol = bn * 256;

    const u16* Abase = A + (size_t)brow * K_IN;
    // per-lane B fragment base: row = bcol + wn*64 + la_lo, k-chunk la_hi*8
    const u16* Bq = B + (size_t)(bcol + wn * 64 + la_lo) * K_IN + la_hi * 8;

    // A staging swizzle (measured 0 conflicts)
    const int srow  = tid >> 3;
    const int sxcol = ((tid & 7) ^ (srow & 7)) * 8;

    // A ds_read swizzled offsets (measured 0 conflicts)
    const int xorr  = la_lo & 7;
    const int aoff0 = la_lo * 64 + ((la_hi    ) ^ xorr) * 8;
    const int aoff1 = la_lo * 64 + ((la_hi + 4) ^ xorr) * 8;

    f32x4 acc[8][4];
    #pragma unroll
    for (int m = 0; m < 8; ++m)
        #pragma unroll
        for (int n = 0; n < 4; ++n)
            acc[m][n] = (f32x4){0.f, 0.f, 0.f, 0.f};

    bf16x8 aR[4][2];
    bf16x8 bX[4], bY[4], bZ[4];

    // Prologue: stage A(0)->buf0 (4 gload_lds, oldest), prefetch B(0,k0)
    STAGE_A(0, 0, 0);
    STAGE_A(0, 1, 0);
    LD_BF(bX, 0, 0);
    VMC0();
    BARM();

    // 64 K-tiles, unroll 2 for register/buffer rotation (static indexing)
    for (int i = 0; i < 32; ++i) {
        const int t0 = 2 * i, t1 = 2 * i + 1;
        TILE(t0, 0, 1, bX, bY, bZ);
        TILE(t1, 1, 0, bZ, bY, bX);
    }

    // Epilogue: C/D layout col = lane&15, row = (lane>>4)*4 + r; add bias
    const int crow0 = brow + wm * 128;
    const int ccol0 = bcol + wn * 64;
    #pragma unroll
    for (int n = 0; n < 4; ++n) {
        const int col = ccol0 + n * 16 + la_lo;
        const float bv = bias[col];
        #pragma unroll
        for (int m = 0; m < 8; ++m) {
            #pragma unroll
            for (int rr = 0; rr < 4; ++rr) {
                const int row = crow0 + m * 16 + la_hi * 4 + rr;
                C[(size_t)row * N_OUT + col] = acc[m][n][rr] + bv;
            }
        }
    }
}

extern "C" void kernel_launch(void* const* d_in, const int* in_sizes, int n_in,
                              void* d_out, int out_size, void* d_ws, size_t ws_size,
                              hipStream_t stream) {
    const float* x     = (const float*)d_in[0];
    const float* mean  = (const float*)d_in[1];
    const float* sigma = (const float*)d_in[2];
    const float* bias  = (const float*)d_in[3];
    const float* noise = (const float*)d_in[4];
    const int*   smult = (const int*)d_in[5];
    float* out = (float*)d_out;

    const size_t x_elems = (size_t)M_TOK * K_IN;
    const size_t w_elems = (size_t)N_OUT * K_IN;
    const size_t need = (x_elems + w_elems) * sizeof(u16);
    if (ws_size < need) return;

    u16* xb = (u16*)d_ws;
    u16* wb = xb + x_elems;

    prep_kernel<<<3072, 256, 0, stream>>>(x, mean, sigma, noise, smult, xb, wb);
    gemm_bias_kernel<<<512, 512, 0, stream>>>(xb, wb, bias, out);
}

// Round 8
// 318.895 us; speedup vs baseline: 1.5373x; 1.5373x over previous
//
#include <hip/hip_runtime.h>
#include <hip/hip_bf16.h>

#define M_TOK 8192
#define N_OUT 4096
#define K_IN  4096

typedef __attribute__((ext_vector_type(8))) short bf16x8;
typedef __attribute__((ext_vector_type(4))) float f32x4;
typedef unsigned short u16;

// fp32 -> bf16 RNE (finite inputs)
__device__ static inline u16 f2bf(float f) {
    union { float f; unsigned int u; } v; v.f = f;
    unsigned int u = v.u;
    u += 0x7FFFu + ((u >> 16) & 1u);
    return (u16)(u >> 16);
}

__device__ static inline void load_lds16(const void* g, void* l) {
    __builtin_amdgcn_global_load_lds(
        (const __attribute__((address_space(1))) unsigned int*)g,
        (__attribute__((address_space(3))) unsigned int*)l,
        16, 0, 0);
}

// ---------------- fused prep pass (memory-bound, ~HBM roofline) -----------
__global__ void prep_kernel(const float* __restrict__ x,
                            const float* __restrict__ mean,
                            const float* __restrict__ sigma,
                            const float* __restrict__ noise,
                            const int* __restrict__ smult,
                            u16* __restrict__ xb, u16* __restrict__ wb) {
    if (blockIdx.x < 2048) {
        const int n4 = (M_TOK * K_IN) / 4;
        int i = blockIdx.x * blockDim.x + threadIdx.x;
        const int stride = 2048 * 256;
        for (int e = i; e < n4; e += stride) {
            float4 v = reinterpret_cast<const float4*>(x)[e];
            ushort4 o;
            o.x = f2bf(v.x); o.y = f2bf(v.y); o.z = f2bf(v.z); o.w = f2bf(v.w);
            reinterpret_cast<ushort4*>(xb)[e] = o;
        }
    } else {
        const float sm = (float)(*smult);
        const int n4 = (N_OUT * K_IN) / 4;
        int i = (blockIdx.x - 2048) * blockDim.x + threadIdx.x;
        const int stride = 1024 * 256;
        for (int e = i; e < n4; e += stride) {
            float4 m = reinterpret_cast<const float4*>(mean)[e];
            float4 s = reinterpret_cast<const float4*>(sigma)[e];
            float4 z = reinterpret_cast<const float4*>(noise)[e];
            ushort4 o;
            o.x = f2bf(m.x * (1.0f + z.x * fabsf(s.x) * sm));
            o.y = f2bf(m.y * (1.0f + z.y * fabsf(s.y) * sm));
            o.z = f2bf(m.z * (1.0f + z.z * fabsf(s.z) * sm));
            o.w = f2bf(m.w * (1.0f + z.w * fabsf(s.w) * sm));
            reinterpret_cast<ushort4*>(wb)[e] = o;
        }
    }
}

// ------ 256x256 GEMM, both operands via LDS, ONE barrier per K-tile -------
// C[t][o] = sum_k A[t][k]*B[o][k] + bias[o]; A=[M][K] bf16, B=[N][K] bf16.
// LDS: [buf(2)][A | B][8192 elem] = 128 KiB. 16B-slot swizzle slot^=(row&7)
// on global src of global_load_lds + on ds_read (measured 0 conflicts).
// Per K-tile: { issue 8 stage loads (t+1 -> buf^1) ; SCHED0 ; 12 ds_reads +
// 64 MFMA compiler-interleaved (counted lgkm) ; vmcnt(0) [loads ~2500cyc old]
// ; barrier }. No intra-tile barriers: waves skew so each SIMD's 2 waves
// overlap LDS (2048cy/tile) under MFMA (2483cy/tile) -> max() not sum().

#define BARM()   { __builtin_amdgcn_s_barrier(); asm volatile("" ::: "memory"); }
#define SCHED0() __builtin_amdgcn_sched_barrier(0)
#define VMC0()   asm volatile("s_waitcnt vmcnt(0)" ::: "memory")

#define DS_A4(AR, MG, AB) \
  _Pragma("unroll") for (int m_ = 0; m_ < 4; ++m_) { \
    AR[m_][0] = *reinterpret_cast<const bf16x8*>((AB) + ((MG)+m_)*1024 + aoff0); \
    AR[m_][1] = *reinterpret_cast<const bf16x8*>((AB) + ((MG)+m_)*1024 + aoff1); }

#define DS_B2(BR, NG, BB) \
  _Pragma("unroll") for (int n_ = 0; n_ < 2; ++n_) { \
    BR[n_][0] = *reinterpret_cast<const bf16x8*>((BB) + ((NG)+n_)*1024 + aoff0); \
    BR[n_][1] = *reinterpret_cast<const bf16x8*>((BB) + ((NG)+n_)*1024 + aoff1); }

#define QUAD(MG, NG, AR, BR) \
  __builtin_amdgcn_s_setprio(1); \
  _Pragma("unroll") for (int m_ = 0; m_ < 4; ++m_) \
  _Pragma("unroll") for (int n_ = 0; n_ < 2; ++n_) { \
    acc[(MG)+m_][(NG)+n_] = __builtin_amdgcn_mfma_f32_16x16x32_bf16( \
        AR[m_][0], BR[n_][0], acc[(MG)+m_][(NG)+n_], 0, 0, 0); \
    acc[(MG)+m_][(NG)+n_] = __builtin_amdgcn_mfma_f32_16x16x32_bf16( \
        AR[m_][1], BR[n_][1], acc[(MG)+m_][(NG)+n_], 0, 0, 0); } \
  __builtin_amdgcn_s_setprio(0);

#define STAGE_A(T, H, BUF) { \
  const u16* g_ = Abase + (size_t)((H)*128 + srow) * K_IN + (T)*64 + sxcol; \
  load_lds16(g_, smem + (BUF)*32768 + (H)*8192 + tid*8); \
  load_lds16(g_ + (size_t)64*K_IN, smem + (BUF)*32768 + (H)*8192 + 4096 + tid*8); }

#define STAGE_B(T, H, BUF) { \
  const u16* g_ = Bbase + (size_t)((H)*128 + srow) * K_IN + (T)*64 + sxcol; \
  load_lds16(g_, smem + (BUF)*32768 + 16384 + (H)*8192 + tid*8); \
  load_lds16(g_ + (size_t)64*K_IN, smem + (BUF)*32768 + 16384 + (H)*8192 + 4096 + tid*8); }

// One K-tile: stage t+1 -> WB, read RB, 64 MFMA, gate, barrier.
#define TILE(T, RB, WB) { \
  const int tn_ = ((T) < 63) ? (T) + 1 : 63; \
  STAGE_A(tn_, 0, WB); STAGE_A(tn_, 1, WB); \
  STAGE_B(tn_, 0, WB); STAGE_B(tn_, 1, WB); \
  SCHED0(); \
  const u16* A_ = smem + (RB)*32768 + wm*8192; \
  const u16* B_ = smem + (RB)*32768 + 16384 + (wn>>1)*8192 + (wn&1)*4096; \
  DS_A4(aR, 0, A_); DS_B2(bA, 0, B_); DS_B2(bB, 2, B_); \
  QUAD(0, 0, aR, bA); QUAD(0, 2, aR, bB); \
  DS_A4(aR, 4, A_); \
  QUAD(4, 2, aR, bB); QUAD(4, 0, aR, bA); \
  VMC0(); BARM(); }

__global__ __launch_bounds__(512, 2)
void gemm_bias_kernel(const u16* __restrict__ A, const u16* __restrict__ B,
                      const float* __restrict__ bias, float* __restrict__ C) {
    __shared__ u16 smem[65536];   // 128 KiB

    const int tid   = threadIdx.x;
    const int lane  = tid & 63;
    const int wid   = tid >> 6;
    const int wm    = wid >> 2;      // 0..1  (M half, 128 rows)
    const int wn    = wid & 3;       // 0..3  (N slice, 64 cols)
    const int la_lo = lane & 15;
    const int la_hi = lane >> 4;

    // T1 v2: per-XCD 2D rectangle (FETCH 197 MB measured, keep)
    const int bid = blockIdx.x;
    const int xcd = bid & 7;
    const int c   = bid >> 3;
    const int r   = c >> 5;
    const int s   = c & 31;
    const int bm  = xcd * 4 + (s & 3);
    const int bn  = r * 8 + (s >> 2);
    const int brow = bm * 256;
    const int bcol = bn * 256;

    const u16* Abase = A + (size_t)brow * K_IN;
    const u16* Bbase = B + (size_t)bcol * K_IN;

    // staging swizzle (measured 0 conflicts)
    const int srow  = tid >> 3;
    const int sxcol = ((tid & 7) ^ (srow & 7)) * 8;

    // ds_read swizzled offsets (measured 0 conflicts)
    const int xorr  = la_lo & 7;
    const int aoff0 = la_lo * 64 + ((la_hi    ) ^ xorr) * 8;
    const int aoff1 = la_lo * 64 + ((la_hi + 4) ^ xorr) * 8;

    f32x4 acc[8][4];
    #pragma unroll
    for (int m = 0; m < 8; ++m)
        #pragma unroll
        for (int n = 0; n < 4; ++n)
            acc[m][n] = (f32x4){0.f, 0.f, 0.f, 0.f};

    bf16x8 aR[4][2], bA[2][2], bB[2][2];

    // Prologue: stage tile0 -> buf0 fully; drain; barrier.
    STAGE_A(0, 0, 0); STAGE_A(0, 1, 0);
    STAGE_B(0, 0, 0); STAGE_B(0, 1, 0);
    VMC0(); BARM();

    // 64 K-tiles, unrolled x2 for static buffer alternation.
    for (int i = 0; i < 32; ++i) {
        TILE(2 * i,     0, 1);
        TILE(2 * i + 1, 1, 0);
    }

    // Epilogue: C/D layout col = lane&15, row = (lane>>4)*4 + r; add bias
    const int crow0 = brow + wm * 128;
    const int ccol0 = bcol + wn * 64;
    #pragma unroll
    for (int n = 0; n < 4; ++n) {
        const int col = ccol0 + n * 16 + la_lo;
        const float bv = bias[col];
        #pragma unroll
        for (int m = 0; m < 8; ++m) {
            #pragma unroll
            for (int rr = 0; rr < 4; ++rr) {
                const int row = crow0 + m * 16 + la_hi * 4 + rr;
                C[(size_t)row * N_OUT + col] = acc[m][n][rr] + bv;
            }
        }
    }
}

extern "C" void kernel_launch(void* const* d_in, const int* in_sizes, int n_in,
                              void* d_out, int out_size, void* d_ws, size_t ws_size,
                              hipStream_t stream) {
    const float* x     = (const float*)d_in[0];
    const float* mean  = (const float*)d_in[1];
    const float* sigma = (const float*)d_in[2];
    const float* bias  = (const float*)d_in[3];
    const float* noise = (const float*)d_in[4];
    const int*   smult = (const int*)d_in[5];
    float* out = (float*)d_out;

    const size_t x_elems = (size_t)M_TOK * K_IN;
    const size_t w_elems = (size_t)N_OUT * K_IN;
    const size_t need = (x_elems + w_elems) * sizeof(u16);
    if (ws_size < need) return;

    u16* xb = (u16*)d_ws;
    u16* wb = xb + x_elems;

    prep_kernel<<<3072, 256, 0, stream>>>(x, mean, sigma, noise, smult, xb, wb);
    gemm_bias_kernel<<<512, 512, 0, stream>>>(xb, wb, bias, out);
}